// Round 6
// baseline (256.354 us; speedup 1.0000x reference)
//
#include <hip/hip_runtime.h>
#include <cstdint>
#include <cstddef>

#define RHO 1e-8f
#define EPSV 1e-8f
#define THRESH 0.9f

typedef float v2f __attribute__((ext_vector_type(2)));

__device__ __forceinline__ float wave_max(float v) {
#pragma unroll
  for (int off = 1; off < 64; off <<= 1) v = fmaxf(v, __shfl_xor(v, off, 64));
  return v;
}

// ---------------- Stage 1: outer_forward -> (maxval, argmax) per (f, b) ------
// v6 = exact r3 revert (51 us, best measured; r4 scatter-loads and r5
// register-pipeline both regressed). One field per 128-thread block; 2 waves
// split the 64 m-rows; XOR-swizzled shared m/x tiles; 4x4 register tile per
// lane. Occupancy-bound at ~6 blocks/CU; leave it alone.
__global__ __launch_bounds__(128) void stage1_kernel(
    const float* __restrict__ xs, const float* __restrict__ mm0,
    float* __restrict__ maxv1, int* __restrict__ idx1) {
  const int tid = threadIdx.x;
  const int lane = tid & 63;
  const int wave = tid >> 6;
  const int f = blockIdx.x;

  __shared__ float mS[64 * 64];  // 16,384 B, swizzled float4 slots
  __shared__ float xS[32 * 64];  // 8,192 B, swizzled float4 slots
  __shared__ float mnS[64];
  __shared__ float xnS[32];
  __shared__ float bestS[2][32];
  __shared__ int bidxS[2][32];

  // ---- stage m tile (shifted by -0.5): 8 float4 per thread, coalesced ----
  const float* mf = mm0 + (size_t)f * 4096;
#pragma unroll
  for (int i = 0; i < 8; ++i) {
    const int g = tid + 128 * i;  // linear float4 index [0,1024)
    const int r = g >> 4, q = g & 15;
    float4 v = *reinterpret_cast<const float4*>(mf + g * 4);
    float4 w = {v.x - 0.5f, v.y - 0.5f, v.z - 0.5f, v.w - 0.5f};
    *reinterpret_cast<float4*>(&mS[(r * 16 + (q ^ (r & 15))) * 4]) = w;
  }
  // ---- stage x tile (shifted by -0.5): 4 float4 per thread ----
  const float* xf = xs + (size_t)f * 64;
#pragma unroll
  for (int i = 0; i < 4; ++i) {
    const int g = tid + 128 * i;  // [0,512)
    const int b = g >> 4, q = g & 15;
    float4 v = *reinterpret_cast<const float4*>(xf + (size_t)b * (4096 * 64) + q * 4);
    float4 w = {v.x - 0.5f, v.y - 0.5f, v.z - 0.5f, v.w - 0.5f};
    *reinterpret_cast<float4*>(&xS[(b * 16 + (q ^ (b & 15))) * 4]) = w;
  }
  __syncthreads();

  // ---- norms: t<64 -> m row t; t in [64,96) -> x row t-64 (one-time) ----
  if (tid < 96) {
    const int r = (tid < 64) ? tid : (tid - 64);
    const float* base = (tid < 64) ? mS : xS;
    v2f s = {0.f, 0.f};
#pragma unroll
    for (int q = 0; q < 16; ++q) {
      float4 v = *reinterpret_cast<const float4*>(&base[(r * 16 + (q ^ (r & 15))) * 4]);
      s = (v2f){v.x, v.y} * (v2f){v.x, v.y} + s;
      s = (v2f){v.z, v.w} * (v2f){v.z, v.w} + s;
    }
    const float n = sqrtf(s.x + s.y);
    if (tid < 64) mnS[r] = n; else xnS[r] = n;
  }
  __syncthreads();

  // ---- K-loop: wave w owns m rows 32w+mg+8i (i<4); lane grid 8mg x 8bg ----
  const int mg = lane >> 3, bg = lane & 7;
  const int mrow0 = wave * 32 + mg;
  v2f acc[4][4][2];
#pragma unroll
  for (int i = 0; i < 4; ++i)
#pragma unroll
    for (int j = 0; j < 4; ++j) {
      acc[i][j][0] = (v2f){0.f, 0.f};
      acc[i][j][1] = (v2f){0.f, 0.f};
    }

#pragma unroll
  for (int d0 = 0; d0 < 64; d0 += 4) {
    const int q = d0 >> 2;
    float4 a[4], bx[4];
#pragma unroll
    for (int i = 0; i < 4; ++i) {
      const int r = mrow0 + 8 * i;
      a[i] = *reinterpret_cast<const float4*>(&mS[(r * 16 + (q ^ (r & 15))) * 4]);
    }
#pragma unroll
    for (int j = 0; j < 4; ++j) {
      const int b = bg + 8 * j;
      bx[j] = *reinterpret_cast<const float4*>(&xS[(b * 16 + (q ^ (b & 15))) * 4]);
    }
#pragma unroll
    for (int i = 0; i < 4; ++i)
#pragma unroll
      for (int j = 0; j < 4; ++j) {
        acc[i][j][0] = (v2f){a[i].x, a[i].y} * (v2f){bx[j].x, bx[j].y} + acc[i][j][0];
        acc[i][j][1] = (v2f){a[i].z, a[i].w} * (v2f){bx[j].z, bx[j].w} + acc[i][j][1];
      }
  }

  // ---- norms from LDS (scalar broadcast-ish reads, 8 total) ----
  float mn_i[4], xn_j[4];
#pragma unroll
  for (int i = 0; i < 4; ++i) mn_i[i] = mnS[mrow0 + 8 * i];
#pragma unroll
  for (int j = 0; j < 4; ++j) xn_j[j] = xnS[bg + 8 * j];

  // ---- vals + in-lane argmax over i (rows ascending -> first-max) ----
  float best[4];
  int bidx[4];
#pragma unroll
  for (int j = 0; j < 4; ++j) { best[j] = -__builtin_inff(); bidx[j] = 0; }
#pragma unroll
  for (int i = 0; i < 4; ++i)
#pragma unroll
    for (int j = 0; j < 4; ++j) {
      const float dot =
          acc[i][j][0].x + acc[i][j][0].y + acc[i][j][1].x + acc[i][j][1].y;
      const float val = (dot * 0.5f) / (mn_i[i] * xn_j[j] + RHO) + 0.5f;
      if (val > best[j]) { best[j] = val; bidx[j] = mrow0 + 8 * i; }
    }
  // ---- cross-lane argmax over mg (xor 8/16/32); ties -> lower m ----
#pragma unroll
  for (int off = 8; off < 64; off <<= 1) {
#pragma unroll
    for (int j = 0; j < 4; ++j) {
      const float pv = __shfl_xor(best[j], off, 64);
      const int pm = __shfl_xor(bidx[j], off, 64);
      if (pv > best[j] || (pv == best[j] && pm < bidx[j])) {
        best[j] = pv; bidx[j] = pm;
      }
    }
  }
  if (mg == 0) {  // lanes 0..7 hold b = bg+8j
#pragma unroll
    for (int j = 0; j < 4; ++j) {
      bestS[wave][bg + 8 * j] = best[j];
      bidxS[wave][bg + 8 * j] = bidx[j];
    }
  }
  __syncthreads();
  if (tid < 32) {  // combine halves; ties -> low half (lower m indices)
    const float v0 = bestS[0][tid], v1 = bestS[1][tid];
    const int i0 = bidxS[0][tid], i1 = bidxS[1][tid];
    const bool take1 = (v1 > v0);
    maxv1[f * 32 + tid] = take1 ? v1 : v0;
    idx1[f * 32 + tid] = take1 ? i1 : i0;
  }
}

// ---------------- Stage 2: hidden_forward (512 nodes) -------------------------
// v6: GATHER, not streaming. child_x is one-hot, so each (n,b) output needs
// only ONE mm1 column per child: w[h] = mm1[n,c,h,k(c,b)] (lane h, stride
// 256 B -> served by L2/L3; mm1 = 33.5 MB is L3-resident across iterations).
// Previous designs streamed the full 128 KB slice per block -- 16x over-read
// and the floor every pipeline variant shared. One wave per (n,b): 16384
// waves, 4096 blocks, ZERO LDS, ZERO barriers -> max occupancy, latency
// hidden by TLP. fmaf chain in c-ascending order, identical to every
// passing round -> bit-exact.
__global__ __launch_bounds__(256) void stage2_kernel(
    const float* __restrict__ maxv_in, const int* __restrict__ idx_in,
    const float* __restrict__ mm,
    float* __restrict__ maxv_out, int* __restrict__ idx_out) {
  const int lane = threadIdx.x & 63;
  const int wave = threadIdx.x >> 6;
  const int p = blockIdx.x * 4 + wave;  // (n,b) pair id, [0, 16384)
  const int node = p >> 5;
  const int b = p & 31;

  // wave-uniform (k, v) table for this (n, b): 8 scalar loads each
  int ks[8];
  float vs[8];
#pragma unroll
  for (int c = 0; c < 8; ++c) {
    const int off = __builtin_amdgcn_readfirstlane((node * 8 + c) * 32 + b);
    ks[c] = idx_in[off];
    vs[c] = maxv_in[off];
  }

  const float* wbase = mm + (size_t)node * (8 * 4096) + (size_t)lane * 64;
  float acc = 0.f, s2 = 0.f;
#pragma unroll
  for (int c = 0; c < 8; ++c) {
    const float w = wbase[c * 4096 + ks[c]];  // gather: one column element
    acc = fmaf(w, vs[c], acc);
    s2 = fmaf(vs[c], vs[c], s2);
  }

  const float val = acc / (8.f * sqrtf(s2) + RHO);
  const float mx = wave_max(val);
  unsigned long long t = __ballot(val == mx);
  int j0 = __ffsll((long long)t) - 1;
  if (lane == 0) {
    maxv_out[node * 32 + b] = mx;  // [node][b]
    idx_out[node * 32 + b] = j0;
  }
}

// ---------------- Stage 3 + growth_argmaxi (fused; exact since round 1) -------
// v6: matmul part replaced by the same one-hot gather (mm2 = 2 MB,
// L2/L3-resident; 64 gathers per lane replace the 128 KB tile stream +
// pipeline + its barriers). c-ascending fmaf order per b preserved ->
// bit-exact. Epilogue (argsort/compaction/one-hot write) unchanged.
__global__ __launch_bounds__(256) void grow_kernel(
    const float* __restrict__ maxv_in, const int* __restrict__ idx_in,
    const float* __restrict__ mm,
    const float* __restrict__ counts, float* __restrict__ out) {
  const int node = blockIdx.x;  // 64 nodes
  const int lane = threadIdx.x & 63;
  const int wave = threadIdx.x >> 6;
  const int tid = threadIdx.x;

  __shared__ float hbuf[32 * 64];
  __shared__ float mxvS[32];
  __shared__ int idxS[32];
  __shared__ int trgS[32];
  __shared__ float cntS[64];
  __shared__ int sidxS[64];
  __shared__ int flagS[64];
  __shared__ int compS[64];
  __shared__ int selS[32];
  __shared__ float valS[32];
  __shared__ int keptS[1];

  const float* wbase = mm + (size_t)node * (8 * 4096) + (size_t)lane * 64;

  float acc[8], s2[8];
#pragma unroll
  for (int i = 0; i < 8; ++i) { acc[i] = 0.f; s2[i] = 0.f; }

#pragma unroll
  for (int i = 0; i < 8; ++i) {
    const int b = wave * 8 + i;
#pragma unroll
    for (int c = 0; c < 8; ++c) {
      const int off = __builtin_amdgcn_readfirstlane((node * 8 + c) * 32 + b);
      const int k = idx_in[off];
      const float v = maxv_in[off];
      const float w = wbase[c * 4096 + k];  // gather
      acc[i] = fmaf(w, v, acc[i]);
      s2[i] = fmaf(v, v, s2[i]);
    }
  }

#pragma unroll
  for (int i = 0; i < 8; ++i) {
    const int b = wave * 8 + i;
    const float val = acc[i] / (8.f * sqrtf(s2[i]) + RHO);
    const float mx = wave_max(val);
    unsigned long long t = __ballot(val == mx);
    int j0 = __ffsll((long long)t) - 1;
    hbuf[b * 64 + lane] = val;
    unsigned long long big = __ballot(val > THRESH);
    if (lane == 0) {
      mxvS[b] = mx; idxS[b] = j0; trgS[b] = (big == 0ULL) ? 1 : 0;
    }
  }

  if (tid < 64) { cntS[tid] = counts[node * 64 + tid]; flagS[tid] = 0; }
  __syncthreads();
  if (tid < 64) {  // stable ascending argsort of counts row
    float cl = cntS[tid];
    int rank = 0;
    for (int j = 0; j < 64; ++j) {
      float cj = cntS[j];
      rank += (cj < cl || (cj == cl && j < tid)) ? 1 : 0;
    }
    sidxS[rank] = tid;
  }
  __syncthreads();
  if (tid < 32) {  // reserved marks from non-triggered batches
    const int b = tid;
    if (!trgS[b]) {
      int j = idxS[b];
      float a = fabsf(mxvS[b]);
      int res;
      if (a > EPSV) res = j;             // unique positive max -> argsort[-1]=j
      else if (a == 0.f) res = 63;       // all-zero row: stable last = 63
      else if (a == EPSV) res = j;       // +inf at j
      else res = (j == 63) ? 62 : 63;    // negative entry: last zero wins
      flagS[res] = 1;
    }
  }
  __syncthreads();
  if (wave == 0) {  // stable compaction (move MARK to back)
    int s = sidxS[lane];
    int keep = flagS[s] ? 0 : 1;
    unsigned long long kb = __ballot(keep);
    int pos = __popcll(kb & ((1ULL << lane) - 1ULL));
    if (keep) compS[pos] = s;
    if (lane == 0) keptS[0] = __popcll(kb);
  }
  __syncthreads();
  if (tid < 32) {  // final index + value per batch
    const int b = tid;
    int fin = (b < keptS[0]) ? compS[b] : sidxS[b];
    int idxb; float a;
    if (trgS[b]) {
      idxb = fin;
      float v = hbuf[b * 64 + idxb];
      if (v == 0.f) v = 1.f;
      a = fabsf(v);
    } else {
      idxb = idxS[b];
      a = fabsf(mxvS[b]);
    }
    selS[b] = idxb;
    valS[b] = a / (a - EPSV);
  }
  __syncthreads();
#pragma unroll
  for (int r = 0; r < 8; ++r) {  // write (32,64) one-hot rows for this node
    int i = tid + 256 * r;
    int b = i >> 6, h = i & 63;
    out[((size_t)b * 64 + node) * 64 + h] = (h == selS[b]) ? valS[b] : 0.f;
  }
}

extern "C" void kernel_launch(void* const* d_in, const int* in_sizes, int n_in,
                              void* d_out, int out_size, void* d_ws, size_t ws_size,
                              hipStream_t stream) {
  const float* xs = (const float*)d_in[0];      // (32, 4096, 64)
  const float* mm0 = (const float*)d_in[1];     // (4096, 64, 64)
  const float* mm1 = (const float*)d_in[2];     // (512, 8, 64, 64)
  const float* mm2 = (const float*)d_in[3];     // (64, 8, 64, 64)
  const float* counts = (const float*)d_in[4];  // (64, 64)
  float* out = (float*)d_out;                   // (32, 64, 64)
  char* ws = (char*)d_ws;

  float* maxv1 = (float*)(ws + 0);        // [4096][32] f32
  int* idx1 = (int*)(ws + 524288);        // [4096][32] i32
  float* maxv2 = (float*)(ws + 1048576);  // [512][32] f32
  int* idx2 = (int*)(ws + 1114112);       // [512][32] i32

  stage1_kernel<<<dim3(4096), dim3(128), 0, stream>>>(xs, mm0, maxv1, idx1);
  stage2_kernel<<<dim3(4096), dim3(256), 0, stream>>>(maxv1, idx1, mm1, maxv2, idx2);
  grow_kernel<<<dim3(64), dim3(256), 0, stream>>>(maxv2, idx2, mm2, counts, out);
}

// Round 7
// 207.175 us; speedup vs baseline: 1.2374x; 1.2374x over previous
//
#include <hip/hip_runtime.h>
#include <cstdint>
#include <cstddef>

#define RHO 1e-8f
#define EPSV 1e-8f
#define THRESH 0.9f

typedef float v2f __attribute__((ext_vector_type(2)));

__device__ __forceinline__ float wave_max(float v) {
#pragma unroll
  for (int off = 1; off < 64; off <<= 1) v = fmaxf(v, __shfl_xor(v, off, 64));
  return v;
}

// Raw workgroup barrier WITHOUT the compiler's vmcnt(0) drain (stage2/grow
// pipeline): only LDS ops must be visible (lgkmcnt(0)); global prefetches
// stay in flight. sched_barrier(0) fences the machine scheduler (rule #18).
__device__ __forceinline__ void lds_barrier() {
  asm volatile("s_waitcnt lgkmcnt(0)" ::: "memory");
  __builtin_amdgcn_sched_barrier(0);
  __builtin_amdgcn_s_barrier();
  __builtin_amdgcn_sched_barrier(0);
}

// global->LDS DMA, 16 B/lane. LDS dest is wave-uniform base + lane*16;
// per-lane global source IS per-lane -> swizzled layouts are achieved by
// pre-swizzling the SOURCE address while keeping LDS linear (m173 pattern).
__device__ __forceinline__ void gll16(const float* gp, float* lp) {
  __builtin_amdgcn_global_load_lds(
      (const __attribute__((address_space(1))) void*)gp,
      (__attribute__((address_space(3))) void*)lp, 16, 0, 0);
}

// ---------------- Stage 1: outer_forward -> (maxval, argmax) per (f, b) ------
// v7 = r3 structure (51 us, best) with staging moved to global_load_lds:
// no register round trip, no load->ds_write serialization -- the 12 staging
// loads per thread become 12 fire-and-forget DMA ops drained once by
// __syncthreads' vmcnt(0). The XOR swizzle (slot(r,q) = r*16 + (q^(r&15)),
// float4 granularity) is applied by PRE-SWIZZLING the global source address;
// each 16-lane group still reads one full 256-B row (permuted within it) ->
// coalescing unchanged, LDS layout byte-identical to r3's. DMA can't apply
// the -0.5 shift, so tiles hold RAW values and -0.5 moves to the consumers
// (identical v_sub_f32 -> identical bits -> bit-exact vs r3).
__global__ __launch_bounds__(128) void stage1_kernel(
    const float* __restrict__ xs, const float* __restrict__ mm0,
    float* __restrict__ maxv1, int* __restrict__ idx1) {
  const int tid = threadIdx.x;
  const int lane = tid & 63;
  const int wave = tid >> 6;
  const int f = blockIdx.x;

  __shared__ float mS[64 * 64];  // 16,384 B, swizzled float4 slots (raw m)
  __shared__ float xS[32 * 64];  // 8,192 B, swizzled float4 slots (raw x)
  __shared__ float mnS[64];
  __shared__ float xnS[32];
  __shared__ float bestS[2][32];
  __shared__ int bidxS[2][32];

  // ---- m tile: 8 DMA calls; call i, lane l -> slot s = i*128 + wave*64 + l.
  // source element (r, q): r = s>>4, q = (s&15) ^ (r&15).
  const float* mf = mm0 + (size_t)f * 4096;
#pragma unroll
  for (int i = 0; i < 8; ++i) {
    const int s = i * 128 + tid;
    const int r = s >> 4;
    const int q = (s & 15) ^ (r & 15);
    gll16(mf + (r * 16 + q) * 4, &mS[(i * 128 + wave * 64) * 4]);
  }
  // ---- x tile: 4 DMA calls, same mapping over b ----
  const float* xf = xs + (size_t)f * 64;
#pragma unroll
  for (int i = 0; i < 4; ++i) {
    const int s = i * 128 + tid;
    const int b = s >> 4;
    const int q = (s & 15) ^ (b & 15);
    gll16(xf + (size_t)b * (4096 * 64) + q * 4, &xS[(i * 128 + wave * 64) * 4]);
  }
  __syncthreads();  // vmcnt(0): all DMA landed; lgkmcnt(0) trivially

  // ---- norms: t<64 -> m row t; t in [64,96) -> x row t-64 (one-time).
  // Subtract-then-square: same v_sub/v_pk_fma ops and order as r3 staged
  // tiles -> bit-identical norms.
  if (tid < 96) {
    const int r = (tid < 64) ? tid : (tid - 64);
    const float* base = (tid < 64) ? mS : xS;
    v2f s = {0.f, 0.f};
#pragma unroll
    for (int q = 0; q < 16; ++q) {
      float4 v = *reinterpret_cast<const float4*>(&base[(r * 16 + (q ^ (r & 15))) * 4]);
      v2f p0 = {v.x - 0.5f, v.y - 0.5f};
      v2f p1 = {v.z - 0.5f, v.w - 0.5f};
      s = p0 * p0 + s;
      s = p1 * p1 + s;
    }
    const float n = sqrtf(s.x + s.y);
    if (tid < 64) mnS[r] = n; else xnS[r] = n;
  }
  __syncthreads();

  // ---- K-loop: wave w owns m rows 32w+mg+8i (i<4); lane grid 8mg x 8bg ----
  const int mg = lane >> 3, bg = lane & 7;
  const int mrow0 = wave * 32 + mg;
  v2f acc[4][4][2];
#pragma unroll
  for (int i = 0; i < 4; ++i)
#pragma unroll
    for (int j = 0; j < 4; ++j) {
      acc[i][j][0] = (v2f){0.f, 0.f};
      acc[i][j][1] = (v2f){0.f, 0.f};
    }

#pragma unroll
  for (int d0 = 0; d0 < 64; d0 += 4) {
    const int q = d0 >> 2;
    float4 a[4], bx[4];
#pragma unroll
    for (int i = 0; i < 4; ++i) {
      const int r = mrow0 + 8 * i;
      float4 v = *reinterpret_cast<const float4*>(&mS[(r * 16 + (q ^ (r & 15))) * 4]);
      a[i] = (float4){v.x - 0.5f, v.y - 0.5f, v.z - 0.5f, v.w - 0.5f};
    }
#pragma unroll
    for (int j = 0; j < 4; ++j) {
      const int b = bg + 8 * j;
      float4 v = *reinterpret_cast<const float4*>(&xS[(b * 16 + (q ^ (b & 15))) * 4]);
      bx[j] = (float4){v.x - 0.5f, v.y - 0.5f, v.z - 0.5f, v.w - 0.5f};
    }
#pragma unroll
    for (int i = 0; i < 4; ++i)
#pragma unroll
      for (int j = 0; j < 4; ++j) {
        acc[i][j][0] = (v2f){a[i].x, a[i].y} * (v2f){bx[j].x, bx[j].y} + acc[i][j][0];
        acc[i][j][1] = (v2f){a[i].z, a[i].w} * (v2f){bx[j].z, bx[j].w} + acc[i][j][1];
      }
  }

  // ---- norms from LDS (scalar broadcast-ish reads, 8 total) ----
  float mn_i[4], xn_j[4];
#pragma unroll
  for (int i = 0; i < 4; ++i) mn_i[i] = mnS[mrow0 + 8 * i];
#pragma unroll
  for (int j = 0; j < 4; ++j) xn_j[j] = xnS[bg + 8 * j];

  // ---- vals + in-lane argmax over i (rows ascending -> first-max) ----
  float best[4];
  int bidx[4];
#pragma unroll
  for (int j = 0; j < 4; ++j) { best[j] = -__builtin_inff(); bidx[j] = 0; }
#pragma unroll
  for (int i = 0; i < 4; ++i)
#pragma unroll
    for (int j = 0; j < 4; ++j) {
      const float dot =
          acc[i][j][0].x + acc[i][j][0].y + acc[i][j][1].x + acc[i][j][1].y;
      const float val = (dot * 0.5f) / (mn_i[i] * xn_j[j] + RHO) + 0.5f;
      if (val > best[j]) { best[j] = val; bidx[j] = mrow0 + 8 * i; }
    }
  // ---- cross-lane argmax over mg (xor 8/16/32); ties -> lower m ----
#pragma unroll
  for (int off = 8; off < 64; off <<= 1) {
#pragma unroll
    for (int j = 0; j < 4; ++j) {
      const float pv = __shfl_xor(best[j], off, 64);
      const int pm = __shfl_xor(bidx[j], off, 64);
      if (pv > best[j] || (pv == best[j] && pm < bidx[j])) {
        best[j] = pv; bidx[j] = pm;
      }
    }
  }
  if (mg == 0) {  // lanes 0..7 hold b = bg+8j
#pragma unroll
    for (int j = 0; j < 4; ++j) {
      bestS[wave][bg + 8 * j] = best[j];
      bidxS[wave][bg + 8 * j] = bidx[j];
    }
  }
  __syncthreads();
  if (tid < 32) {  // combine halves; ties -> low half (lower m indices)
    const float v0 = bestS[0][tid], v1 = bestS[1][tid];
    const int i0 = bidxS[0][tid], i1 = bidxS[1][tid];
    const bool take1 = (v1 > v0);
    maxv1[f * 32 + tid] = take1 ? v1 : v0;
    idx1[f * 32 + tid] = take1 ? i1 : i0;
  }
}

// -------- shared pipeline macros for stage2/grow (1 child = 16 KB tile) -----
// Swizzled layout per child: element (h,k) at [k*64 + (h^k)] -> staging
// writes and per-(b) column reads are conflict-free. (Reverted verbatim to
// the r4 streaming versions; r6's gather caused 16x sector over-fetch,
// 256 MB FETCH_SIZE, 72 us.)
#define STAGE_WRITE(T, R)                                    \
  do {                                                       \
    _Pragma("unroll") for (int i_ = 0; i_ < 4; ++i_) {       \
      const int g_ = tid + 256 * i_;                         \
      const int h_ = g_ >> 4, k0_ = (g_ & 15) * 4;           \
      (T)[(k0_ + 0) * 64 + (h_ ^ (k0_ + 0))] = (R)[i_].x;    \
      (T)[(k0_ + 1) * 64 + (h_ ^ (k0_ + 1))] = (R)[i_].y;    \
      (T)[(k0_ + 2) * 64 + (h_ ^ (k0_ + 2))] = (R)[i_].z;    \
      (T)[(k0_ + 3) * 64 + (h_ ^ (k0_ + 3))] = (R)[i_].w;    \
    }                                                        \
  } while (0)

#define LOAD_CHILD(R, C)                                     \
  do {                                                       \
    _Pragma("unroll") for (int i_ = 0; i_ < 4; ++i_)         \
        (R)[i_] = src[(C) * 1024 + tid + 256 * i_];          \
  } while (0)

#define COMPUTE_CHILD(C, T)                                              \
  do {                                                                   \
    _Pragma("unroll") for (int i_ = 0; i_ < 8; ++i_) {                   \
      const int b_ = wave * 8 + i_;                                      \
      const int k_ = ixL[(C) * 32 + b_];                                 \
      const float v_ = mvL[(C) * 32 + b_];                               \
      const float w_ = (T)[k_ * 64 + (lane ^ k_)];                       \
      acc[i_] = fmaf(w_, v_, acc[i_]);                                   \
      s2[i_] = fmaf(v_, v_, s2[i_]);                                     \
    }                                                                    \
  } while (0)

// 8-phase register-staged 2-deep pipeline with NON-DRAINING barriers.
// Summation order over c unchanged -> bit-identical accumulate.
#define PIPELINE_MATMUL()                        \
  do {                                           \
    float4 rE[4], rO[4];                         \
    LOAD_CHILD(rE, 0);                           \
    LOAD_CHILD(rO, 1);                           \
    STAGE_WRITE(tA, rE);                         \
    lds_barrier();                               \
    _Pragma("unroll") for (int cc = 0; cc < 8; cc += 2) { \
      if (cc + 2 < 8) LOAD_CHILD(rE, cc + 2);    \
      COMPUTE_CHILD(cc, tA);                     \
      STAGE_WRITE(tB, rO);                       \
      lds_barrier();                             \
      if (cc + 3 < 8) LOAD_CHILD(rO, cc + 3);    \
      COMPUTE_CHILD(cc + 1, tB);                 \
      if (cc + 2 < 8) { STAGE_WRITE(tA, rE); }   \
      lds_barrier();                             \
    }                                            \
  } while (0)

// ---------------- Stage 2: hidden_forward (512 nodes) -------------------------
__global__ __launch_bounds__(256) void stage2_kernel(
    const float* __restrict__ maxv_in, const int* __restrict__ idx_in,
    const float* __restrict__ mm,
    float* __restrict__ maxv_out, int* __restrict__ idx_out) {
  const int node = blockIdx.x;
  const int lane = threadIdx.x & 63;
  const int wave = threadIdx.x >> 6;
  const int tid = threadIdx.x;

  __shared__ float tA[4096], tB[4096];  // 32 KB double buffer
  __shared__ float mvL[256];
  __shared__ int ixL[256];

  const float4* src = reinterpret_cast<const float4*>(mm + (size_t)node * (8 * 4096));

  // preload the full (c,b) index/value table for this node (coalesced);
  // made visible by the first lds_barrier's lgkmcnt(0).
  mvL[tid] = maxv_in[node * 256 + tid];
  ixL[tid] = idx_in[node * 256 + tid];

  float acc[8], s2[8];
#pragma unroll
  for (int i = 0; i < 8; ++i) { acc[i] = 0.f; s2[i] = 0.f; }

  PIPELINE_MATMUL();

#pragma unroll
  for (int i = 0; i < 8; ++i) {
    const int b = wave * 8 + i;
    const float val = acc[i] / (8.f * sqrtf(s2[i]) + RHO);
    const float mx = wave_max(val);
    unsigned long long t = __ballot(val == mx);
    int j0 = __ffsll((long long)t) - 1;
    if (lane == 0) {
      maxv_out[node * 32 + b] = mx;  // [node][b]
      idx_out[node * 32 + b] = j0;
    }
  }
}

// ---------------- Stage 3 + growth_argmaxi (fused; exact since round 1) -------
__global__ __launch_bounds__(256) void grow_kernel(
    const float* __restrict__ maxv_in, const int* __restrict__ idx_in,
    const float* __restrict__ mm,
    const float* __restrict__ counts, float* __restrict__ out) {
  const int node = blockIdx.x;  // 64 nodes
  const int lane = threadIdx.x & 63;
  const int wave = threadIdx.x >> 6;
  const int tid = threadIdx.x;

  __shared__ float tA[4096], tB[4096];  // 32 KB double buffer
  __shared__ float mvL[256];
  __shared__ int ixL[256];
  __shared__ float hbuf[32 * 64];
  __shared__ float mxvS[32];
  __shared__ int idxS[32];
  __shared__ int trgS[32];
  __shared__ float cntS[64];
  __shared__ int sidxS[64];
  __shared__ int flagS[64];
  __shared__ int compS[64];
  __shared__ int selS[32];
  __shared__ float valS[32];
  __shared__ int keptS[1];

  const float4* src = reinterpret_cast<const float4*>(mm + (size_t)node * (8 * 4096));

  mvL[tid] = maxv_in[node * 256 + tid];
  ixL[tid] = idx_in[node * 256 + tid];

  float acc[8], s2[8];
#pragma unroll
  for (int i = 0; i < 8; ++i) { acc[i] = 0.f; s2[i] = 0.f; }

  PIPELINE_MATMUL();

#pragma unroll
  for (int i = 0; i < 8; ++i) {
    const int b = wave * 8 + i;
    const float val = acc[i] / (8.f * sqrtf(s2[i]) + RHO);
    const float mx = wave_max(val);
    unsigned long long t = __ballot(val == mx);
    int j0 = __ffsll((long long)t) - 1;
    hbuf[b * 64 + lane] = val;
    unsigned long long big = __ballot(val > THRESH);
    if (lane == 0) {
      mxvS[b] = mx; idxS[b] = j0; trgS[b] = (big == 0ULL) ? 1 : 0;
    }
  }

  if (tid < 64) { cntS[tid] = counts[node * 64 + tid]; flagS[tid] = 0; }
  __syncthreads();
  if (tid < 64) {  // stable ascending argsort of counts row
    float cl = cntS[tid];
    int rank = 0;
    for (int j = 0; j < 64; ++j) {
      float cj = cntS[j];
      rank += (cj < cl || (cj == cl && j < tid)) ? 1 : 0;
    }
    sidxS[rank] = tid;
  }
  __syncthreads();
  if (tid < 32) {  // reserved marks from non-triggered batches
    const int b = tid;
    if (!trgS[b]) {
      int j = idxS[b];
      float a = fabsf(mxvS[b]);
      int res;
      if (a > EPSV) res = j;             // unique positive max -> argsort[-1]=j
      else if (a == 0.f) res = 63;       // all-zero row: stable last = 63
      else if (a == EPSV) res = j;       // +inf at j
      else res = (j == 63) ? 62 : 63;    // negative entry: last zero wins
      flagS[res] = 1;
    }
  }
  __syncthreads();
  if (wave == 0) {  // stable compaction (move MARK to back)
    int s = sidxS[lane];
    int keep = flagS[s] ? 0 : 1;
    unsigned long long kb = __ballot(keep);
    int pos = __popcll(kb & ((1ULL << lane) - 1ULL));
    if (keep) compS[pos] = s;
    if (lane == 0) keptS[0] = __popcll(kb);
  }
  __syncthreads();
  if (tid < 32) {  // final index + value per batch
    const int b = tid;
    int fin = (b < keptS[0]) ? compS[b] : sidxS[b];
    int idxb; float a;
    if (trgS[b]) {
      idxb = fin;
      float v = hbuf[b * 64 + idxb];
      if (v == 0.f) v = 1.f;
      a = fabsf(v);
    } else {
      idxb = idxS[b];
      a = fabsf(mxvS[b]);
    }
    selS[b] = idxb;
    valS[b] = a / (a - EPSV);
  }
  __syncthreads();
#pragma unroll
  for (int r = 0; r < 8; ++r) {  // write (32,64) one-hot rows for this node
    int i = tid + 256 * r;
    int b = i >> 6, h = i & 63;
    out[((size_t)b * 64 + node) * 64 + h] = (h == selS[b]) ? valS[b] : 0.f;
  }
}

extern "C" void kernel_launch(void* const* d_in, const int* in_sizes, int n_in,
                              void* d_out, int out_size, void* d_ws, size_t ws_size,
                              hipStream_t stream) {
  const float* xs = (const float*)d_in[0];      // (32, 4096, 64)
  const float* mm0 = (const float*)d_in[1];     // (4096, 64, 64)
  const float* mm1 = (const float*)d_in[2];     // (512, 8, 64, 64)
  const float* mm2 = (const float*)d_in[3];     // (64, 8, 64, 64)
  const float* counts = (const float*)d_in[4];  // (64, 64)
  float* out = (float*)d_out;                   // (32, 64, 64)
  char* ws = (char*)d_ws;

  float* maxv1 = (float*)(ws + 0);        // [4096][32] f32
  int* idx1 = (int*)(ws + 524288);        // [4096][32] i32
  float* maxv2 = (float*)(ws + 1048576);  // [512][32] f32
  int* idx2 = (int*)(ws + 1114112);       // [512][32] i32

  stage1_kernel<<<dim3(4096), dim3(128), 0, stream>>>(xs, mm0, maxv1, idx1);
  stage2_kernel<<<dim3(512), dim3(256), 0, stream>>>(maxv1, idx1, mm1, maxv2, idx2);
  grow_kernel<<<dim3(64), dim3(256), 0, stream>>>(maxv2, idx2, mm2, counts, out);
}